// Round 2
// baseline (124.481 us; speedup 1.0000x reference)
//
#include <hip/hip_runtime.h>

#define BSZ 32
#define SLEN 2048
#define NVAL 256
#define CHUNK 64   // positions per block in main kernel

// out[c*rows + d] = in[d*in_ld + col0 + c]
__global__ __launch_bounds__(256) void k_transpose(const float* __restrict__ in,
                                                   float* __restrict__ out,
                                                   int rows, int in_ld, int col0) {
  __shared__ float tile[64][65];
  int c0 = blockIdx.x * 64, d0 = blockIdx.y * 64;
  int tx = threadIdx.x & 63, ty = threadIdx.x >> 6;
#pragma unroll
  for (int j = 0; j < 16; ++j) {
    int dd = ty + j * 4;
    tile[dd][tx] = in[(d0 + dd) * in_ld + col0 + c0 + tx];
  }
  __syncthreads();
#pragma unroll
  for (int j = 0; j < 16; ++j) {
    int cc = ty + j * 4;
    out[(c0 + cc) * rows + d0 + tx] = tile[tx][cc];
  }
}

// Tb[k][d] = Wk_b[d] + sum_e W2T[e][d] * embK[k][e]   (8 k's per block)
__global__ __launch_bounds__(256) void k_build_T(const float* __restrict__ W2T,
                                                 const float* __restrict__ embK,
                                                 const float* __restrict__ Wk_b,
                                                 float* __restrict__ Tb) {
  __shared__ float emb[8 * 256];
  int tid = threadIdx.x;
  int k0 = blockIdx.x * 8;
#pragma unroll
  for (int t = 0; t < 8; ++t) emb[tid + t * 256] = embK[k0 * 256 + tid + t * 256];
  __syncthreads();
  float acc[8] = {0.f, 0.f, 0.f, 0.f, 0.f, 0.f, 0.f, 0.f};
  for (int e = 0; e < 256; ++e) {
    float wv = W2T[e * 256 + tid];
#pragma unroll
    for (int j = 0; j < 8; ++j) acc[j] += wv * emb[j * 256 + e];
  }
  float bias = Wk_b[tid];
#pragma unroll
  for (int j = 0; j < 8; ++j) Tb[(k0 + j) * 256 + tid] = acc[j] + bias;
}

// Qp[b][p] : dpfp of (Wq_w @ embK[q[b]] + Wq_b)
__global__ __launch_bounds__(256) void k_build_Q(const int* __restrict__ q,
                                                 const float* __restrict__ WqT,
                                                 const float* __restrict__ Wq_b,
                                                 const float* __restrict__ embK,
                                                 float* __restrict__ Qp) {
  __shared__ float qe[256];
  __shared__ float xq[512];
  int b = blockIdx.x, tid = threadIdx.x;
  qe[tid] = embK[q[b] * 256 + tid];
  __syncthreads();
  float acc = Wq_b[tid];
  for (int e = 0; e < 256; ++e) acc += WqT[e * 256 + tid] * qe[e];
  xq[tid] = fmaxf(acc, 0.f);
  xq[tid + 256] = fmaxf(-acc, 0.f);
  __syncthreads();
#pragma unroll
  for (int t = 0; t < 4; ++t) {
    int p = tid + t * 256;
    float v = (p < 512) ? xq[p] * xq[(p - 1) & 511]
                        : xq[p - 512] * xq[(p - 514) & 511];
    Qp[b * 1024 + p] = v;
  }
}

// main: register/shuffle-only per-position dpfp dot (no cross-lane LDS hazard).
// Lane L owns x' indices i = hf*256 + (L&31)*8 + j, j=0..7  (hf = L>>5).
// Consecutive lanes hold consecutive 8-blocks of i, so x'_{i-1}/x'_{i-2} come
// from in-lane registers except j=0/1, which take lane L-1's xp[7]/xp[6] via shfl
// (lane 0 wraps to lane 63 = x'_{511}, x'_{510}, matching jnp.roll).
__global__ __launch_bounds__(256) void k_main(const int* __restrict__ x,
                                              const float* __restrict__ Wv,
                                              const float* __restrict__ Tb,
                                              const float* __restrict__ Qp,
                                              float* __restrict__ num,
                                              float* __restrict__ den) {
  __shared__ float numW[4][256];
  __shared__ float denW[4];
  const int nchunks = SLEN / CHUNK;
  int tid = threadIdx.x;
  int lane = tid & 63, w = tid >> 6;
  int b = blockIdx.x / nchunks, chunk = blockIdx.x % nchunks;
  int hf = lane >> 5;
  int dbase = (lane & 31) * 8;
  int ibase = hf * 256 + dbase;

#pragma unroll
  for (int t = 0; t < 4; ++t) ((float*)numW)[tid + t * 256] = 0.f;
  __syncthreads();

  const float* Qb = Qp + b * 1024;
  float Q1r[8], Q2r[8];
  {
    float4 a0 = *(const float4*)(Qb + ibase);
    float4 a1 = *(const float4*)(Qb + ibase + 4);
    float4 c0 = *(const float4*)(Qb + 512 + ibase);
    float4 c1 = *(const float4*)(Qb + 512 + ibase + 4);
    Q1r[0] = a0.x; Q1r[1] = a0.y; Q1r[2] = a0.z; Q1r[3] = a0.w;
    Q1r[4] = a1.x; Q1r[5] = a1.y; Q1r[6] = a1.z; Q1r[7] = a1.w;
    Q2r[0] = c0.x; Q2r[1] = c0.y; Q2r[2] = c0.z; Q2r[3] = c0.w;
    Q2r[4] = c1.x; Q2r[5] = c1.y; Q2r[6] = c1.z; Q2r[7] = c1.w;
  }

  const int* xb = x + b * 2 * SLEN;
  float dloc = 0.f;
  int l0 = chunk * CHUNK;
  for (int l = l0 + w; l < l0 + CHUNK; l += 4) {
    int key = xb[l];                    // wave-uniform
    int vcol = xb[SLEN + l] - NVAL;     // wave-uniform
    const float* Wr = Wv + vcol * 256 + dbase;
    const float* Tr = Tb + key * 256 + dbase;
    float4 w0 = *(const float4*)(Wr);
    float4 w1 = *(const float4*)(Wr + 4);
    float4 t0 = *(const float4*)(Tr);
    float4 t1 = *(const float4*)(Tr + 4);
    float y[8] = {w0.x + t0.x, w0.y + t0.y, w0.z + t0.z, w0.w + t0.w,
                  w1.x + t1.x, w1.y + t1.y, w1.z + t1.z, w1.w + t1.w};
    float xp[8];
#pragma unroll
    for (int j = 0; j < 8; ++j) xp[j] = hf ? fmaxf(-y[j], 0.f) : fmaxf(y[j], 0.f);
    int src = (lane + 63) & 63;
    float prev1 = __shfl(xp[7], src, 64);
    float prev2 = __shfl(xp[6], src, 64);
    float s = xp[0] * (prev1 * Q1r[0] + prev2 * Q2r[0])
            + xp[1] * (xp[0] * Q1r[1] + prev1 * Q2r[1]);
#pragma unroll
    for (int j = 2; j < 8; ++j) s += xp[j] * (xp[j - 1] * Q1r[j] + xp[j - 2] * Q2r[j]);
#pragma unroll
    for (int off = 32; off >= 1; off >>= 1) s += __shfl_xor(s, off, 64);
    if (lane == 0) { numW[w][vcol] += s; dloc += s; }
  }
  if (lane == 0) denW[w] = dloc;
  __syncthreads();
  float tsum = numW[0][tid] + numW[1][tid] + numW[2][tid] + numW[3][tid];
  atomicAdd(&num[b * 256 + tid], tsum);
  if (tid == 0) atomicAdd(&den[b], denW[0] + denW[1] + denW[2] + denW[3]);
}

__global__ __launch_bounds__(256) void k_final(const float* __restrict__ num,
                                               const float* __restrict__ den,
                                               float* __restrict__ out) {
  int b = blockIdx.x, v = threadIdx.x;
  out[b * 256 + v] = num[b * 256 + v] / (den[b] + 1e-6f);
}

extern "C" void kernel_launch(void* const* d_in, const int* in_sizes, int n_in,
                              void* d_out, int out_size, void* d_ws, size_t ws_size,
                              hipStream_t stream) {
  const int* x = (const int*)d_in[0];
  const int* q = (const int*)d_in[1];
  const float* embK = (const float*)d_in[2];
  const float* Wk_w = (const float*)d_in[3];
  const float* Wk_b = (const float*)d_in[4];
  const float* Wq_w = (const float*)d_in[5];
  const float* Wq_b = (const float*)d_in[6];
  float* out = (float*)d_out;

  char* ws = (char*)d_ws;
  float* W2T = (float*)ws; ws += 256 * 256 * 4;   // Wk_w right half, transposed
  float* Wv  = (float*)ws; ws += 256 * 256 * 4;   // Wk_w left half, transposed
  float* WqT = (float*)ws; ws += 256 * 256 * 4;   // Wq_w transposed
  float* Tb  = (float*)ws; ws += 512 * 256 * 4;   // key table (+bias)
  float* Qp  = (float*)ws; ws += 32 * 1024 * 4;   // dpfp'd queries
  float* num = (float*)ws; ws += 32 * 256 * 4;
  float* den = (float*)ws; ws += 32 * 4;

  hipMemsetAsync(num, 0, (32 * 256 + 32) * 4, stream);  // num+den contiguous

  dim3 blk(256);
  k_transpose<<<dim3(4, 4), blk, 0, stream>>>(Wk_w, W2T, 256, 512, 256);
  k_transpose<<<dim3(4, 4), blk, 0, stream>>>(Wk_w, Wv, 256, 512, 0);
  k_transpose<<<dim3(4, 4), blk, 0, stream>>>(Wq_w, WqT, 256, 256, 0);
  k_build_T<<<64, blk, 0, stream>>>(W2T, embK, Wk_b, Tb);
  k_build_Q<<<32, blk, 0, stream>>>(q, WqT, Wq_b, embK, Qp);
  k_main<<<BSZ * (SLEN / CHUNK), blk, 0, stream>>>(x, Wv, Tb, Qp, num, den);
  k_final<<<32, 256, 0, stream>>>(num, den, out);
}

// Round 5
// 91.910 us; speedup vs baseline: 1.3544x; 1.3544x over previous
//
#include <hip/hip_runtime.h>

#define BSZ 32
#define SLEN 2048
#define NVAL 256
#define CHUNK 32                 // positions per k_main block
#define NCHUNK (SLEN / CHUNK)    // 64

// ---------------------------------------------------------------------------
// Kernel A: fused precompute.
//   blocks 0..15  : Wv[c][d] = Wk_w[d][c]          (transpose of left half)
//   blocks 16..79 : Tb[k][d] = Wk_b[d] + sum_e Wk_w[d][256+e]*embK[k][e]
//   blocks 80..111: Qp[b][*] = dpfp(Wq_w @ embK[q[b]] + Wq_b)
// ---------------------------------------------------------------------------
__global__ __launch_bounds__(256) void k_pre(const int* __restrict__ q,
                                             const float* __restrict__ embK,
                                             const float* __restrict__ Wk_w,
                                             const float* __restrict__ Wk_b,
                                             const float* __restrict__ Wq_w,
                                             const float* __restrict__ Wq_b,
                                             float* __restrict__ Wv,
                                             float* __restrict__ Tb,
                                             float* __restrict__ Qp) {
  __shared__ float smem[64 * 65];
  int bx = blockIdx.x, tid = threadIdx.x;

  if (bx < 16) {
    // ---- transpose left 256 cols of Wk_w into Wv (64x64 tiles) ----
    float (*tile)[65] = (float(*)[65])smem;
    int c0 = (bx & 3) * 64, d0 = (bx >> 2) * 64;
    int tx = tid & 63, ty = tid >> 6;
#pragma unroll
    for (int j = 0; j < 16; ++j) {
      int dd = ty + j * 4;
      tile[dd][tx] = Wk_w[(d0 + dd) * 512 + c0 + tx];
    }
    __syncthreads();
#pragma unroll
    for (int j = 0; j < 16; ++j) {
      int cc = ty + j * 4;
      Wv[(c0 + cc) * 256 + d0 + tx] = tile[tx][cc];
    }
  } else if (bx < 80) {
    // ---- Tb build: 8 keys per block, transpose-free ----
    int k0 = (bx - 16) * 8;
    float* emb = smem;  // 8*256
#pragma unroll
    for (int t = 0; t < 8; ++t) emb[t * 256 + tid] = embK[(k0 + t) * 256 + tid];
    __syncthreads();
    float acc[8] = {0.f, 0.f, 0.f, 0.f, 0.f, 0.f, 0.f, 0.f};
    const float* wr = Wk_w + tid * 512 + 256;  // thread tid = output dim d
    for (int e4 = 0; e4 < 64; ++e4) {
      float4 wv = *(const float4*)(wr + e4 * 4);
      const float wvf[4] = {wv.x, wv.y, wv.z, wv.w};
#pragma unroll
      for (int jj = 0; jj < 4; ++jj) {
        float we = wvf[jj];
        int e = e4 * 4 + jj;
#pragma unroll
        for (int k = 0; k < 8; ++k) acc[k] += we * emb[k * 256 + e];
      }
    }
    float bias = Wk_b[tid];
#pragma unroll
    for (int k = 0; k < 8; ++k) Tb[(k0 + k) * 256 + tid] = acc[k] + bias;
  } else {
    // ---- Qp build: one query per block, transpose-free ----
    int b = bx - 80;
    float* qe = smem;        // 256
    float* xq = smem + 256;  // 512
    qe[tid] = embK[q[b] * 256 + tid];
    __syncthreads();
    float acc = Wq_b[tid];
    const float* wr = Wq_w + tid * 256;
    for (int e4 = 0; e4 < 64; ++e4) {
      float4 wv = *(const float4*)(wr + e4 * 4);
      int e = e4 * 4;
      acc += wv.x * qe[e] + wv.y * qe[e + 1] + wv.z * qe[e + 2] + wv.w * qe[e + 3];
    }
    xq[tid] = fmaxf(acc, 0.f);
    xq[tid + 256] = fmaxf(-acc, 0.f);
    __syncthreads();
#pragma unroll
    for (int t = 0; t < 4; ++t) {
      int p = tid + t * 256;
      float v = (p < 512) ? xq[p] * xq[(p - 1) & 511]
                          : xq[p - 512] * xq[(p - 514) & 511];
      Qp[b * 1024 + p] = v;
    }
  }
}

// ---------------------------------------------------------------------------
// Kernel B: main scoring. Lane L owns d in [4L,4L+4); computes both relu
// halves in registers (x'_i: i<256 -> xp0, i>=256 -> xp1). Roll neighbors via
// 4 shuffles from lane-1; lane 0's wraparound swaps halves. One scalar score
// per position -> dense per-chunk partials numP[b][chunk][v], no atomics.
// ---------------------------------------------------------------------------
__global__ __launch_bounds__(256) void k_main(const int* __restrict__ x,
                                              const float* __restrict__ Wv,
                                              const float* __restrict__ Tb,
                                              const float* __restrict__ Qp,
                                              float* __restrict__ numP) {
  __shared__ float numW[4][256];
  __shared__ int kidx[CHUNK], vidx[CHUNK];
  int tid = threadIdx.x;
  int lane = tid & 63, w = tid >> 6;
  int b = blockIdx.x / NCHUNK, chunk = blockIdx.x % NCHUNK;
  int l0 = chunk * CHUNK;
  const int* xb = x + b * 2 * SLEN;

  if (tid < CHUNK) kidx[tid] = xb[l0 + tid];
  else if (tid < 2 * CHUNK) vidx[tid - CHUNK] = xb[SLEN + l0 + tid - CHUNK];
#pragma unroll
  for (int t = 0; t < 4; ++t) ((float*)numW)[tid + t * 256] = 0.f;
  __syncthreads();

  const float* Qb = Qp + b * 1024 + 4 * lane;
  float4 qa = *(const float4*)(Qb);        // Q[4L+j]        (half0, x_{i-1})
  float4 qc = *(const float4*)(Qb + 256);  // Q[256+4L+j]    (half1, x_{i-1})
  float4 qb4 = *(const float4*)(Qb + 512); // Q[512+4L+j]    (half0, x_{i-2})
  float4 qd = *(const float4*)(Qb + 768);  // Q[768+4L+j]    (half1, x_{i-2})
  const float QA[4] = {qa.x, qa.y, qa.z, qa.w};
  const float QC[4] = {qc.x, qc.y, qc.z, qc.w};
  const float QB[4] = {qb4.x, qb4.y, qb4.z, qb4.w};
  const float QD[4] = {qd.x, qd.y, qd.z, qd.w};

  int src = (lane + 63) & 63;
  bool l0lane = (lane == 0);

  for (int p8 = 0; p8 < CHUNK / 4; ++p8) {
    int l = w + p8 * 4;
    int key = kidx[l];
    int vcol = vidx[l] - NVAL;
    float4 wv = *(const float4*)(Wv + vcol * 256 + 4 * lane);
    float4 tv = *(const float4*)(Tb + key * 256 + 4 * lane);
    float y[4] = {wv.x + tv.x, wv.y + tv.y, wv.z + tv.z, wv.w + tv.w};
    float xp0[4], xp1[4];
#pragma unroll
    for (int j = 0; j < 4; ++j) {
      xp0[j] = fmaxf(y[j], 0.f);
      xp1[j] = fmaxf(-y[j], 0.f);
    }
    float p0_3 = __shfl(xp0[3], src, 64);
    float p0_2 = __shfl(xp0[2], src, 64);
    float p1_3 = __shfl(xp1[3], src, 64);
    float p1_2 = __shfl(xp1[2], src, 64);
    // lane 0 wraps across halves: x_{-1}=x_{511} (xp1 of lane 63), x_{255} (xp0 of lane 63)
    float h0p1 = l0lane ? p1_3 : p0_3;
    float h0p2 = l0lane ? p1_2 : p0_2;
    float h1p1 = l0lane ? p0_3 : p1_3;
    float h1p2 = l0lane ? p0_2 : p1_2;

    float s = xp0[0] * (h0p1 * QA[0] + h0p2 * QB[0])
            + xp0[1] * (xp0[0] * QA[1] + h0p1 * QB[1])
            + xp0[2] * (xp0[1] * QA[2] + xp0[0] * QB[2])
            + xp0[3] * (xp0[2] * QA[3] + xp0[1] * QB[3])
            + xp1[0] * (h1p1 * QC[0] + h1p2 * QD[0])
            + xp1[1] * (xp1[0] * QC[1] + h1p1 * QD[1])
            + xp1[2] * (xp1[1] * QC[2] + xp1[0] * QD[2])
            + xp1[3] * (xp1[2] * QC[3] + xp1[1] * QD[3]);
#pragma unroll
    for (int off = 32; off >= 1; off >>= 1) s += __shfl_xor(s, off, 64);
    if (lane == 0) numW[w][vcol] += s;
  }
  __syncthreads();
  float tsum = numW[0][tid] + numW[1][tid] + numW[2][tid] + numW[3][tid];
  numP[(b * NCHUNK + chunk) * 256 + tid] = tsum;
}

// ---------------------------------------------------------------------------
// Kernel C: reduce partials over chunks; den[b] = sum_v num[b][v]; divide.
// ---------------------------------------------------------------------------
__global__ __launch_bounds__(256) void k_final(const float* __restrict__ numP,
                                               float* __restrict__ out) {
  __shared__ float red[256];
  int b = blockIdx.x, v = threadIdx.x;
  float acc = 0.f;
  const float* p = numP + b * NCHUNK * 256 + v;
  for (int c = 0; c < NCHUNK; ++c) acc += p[c * 256];
  red[v] = acc;
  __syncthreads();
  if (v < 128) red[v] += red[v + 128];
  __syncthreads();
  if (v < 64) {
    float r = red[v] + red[v + 64];
#pragma unroll
    for (int off = 32; off >= 1; off >>= 1) r += __shfl_xor(r, off, 64);
    if (v == 0) red[0] = r;
  }
  __syncthreads();
  out[b * 256 + v] = acc / (red[0] + 1e-6f);
}

extern "C" void kernel_launch(void* const* d_in, const int* in_sizes, int n_in,
                              void* d_out, int out_size, void* d_ws, size_t ws_size,
                              hipStream_t stream) {
  const int* x = (const int*)d_in[0];
  const int* q = (const int*)d_in[1];
  const float* embK = (const float*)d_in[2];
  const float* Wk_w = (const float*)d_in[3];
  const float* Wk_b = (const float*)d_in[4];
  const float* Wq_w = (const float*)d_in[5];
  const float* Wq_b = (const float*)d_in[6];
  float* out = (float*)d_out;

  char* ws = (char*)d_ws;
  float* Wv   = (float*)ws; ws += 256 * 256 * 4;        // transposed left half of Wk_w
  float* Tb   = (float*)ws; ws += 512 * 256 * 4;        // key table (+bias)
  float* Qp   = (float*)ws; ws += 32 * 1024 * 4;        // dpfp'd queries
  float* numP = (float*)ws; ws += 32 * NCHUNK * 256 * 4; // per-chunk partials

  dim3 blk(256);
  k_pre<<<112, blk, 0, stream>>>(q, embK, Wk_w, Wk_b, Wq_w, Wq_b, Wv, Tb, Qp);
  k_main<<<BSZ * NCHUNK, blk, 0, stream>>>(x, Wv, Tb, Qp, numP);
  k_final<<<BSZ, blk, 0, stream>>>(numP, out);
}